// Round 6
// baseline (433.904 us; speedup 1.0000x reference)
//
#include <hip/hip_runtime.h>

constexpr int NN = 100000;   // nodes
constexpr int DI = 256;      // in features
constexpr int DO = 128;      // out features
constexpr int NE = 1600000;  // edges

constexpr int BROWS = 128;                        // rows per bucket
constexpr int NBK   = (NN + BROWS - 1) / BROWS;   // 782 buckets
constexpr int TILE  = 2048;                       // edges per partition block (R6: 8192->2048, 196->782 blocks)
constexpr int CAP   = 2688;                       // slots per bucket (mean 2046, sd ~45)

typedef __bf16 bf16x8 __attribute__((ext_vector_type(8)));
typedef float  f32x4  __attribute__((ext_vector_type(4)));

__device__ inline unsigned short f2bf(float f) {
    union { float f; unsigned u; } v; v.f = f;
    return (unsigned short)((v.u + 0x7FFF + ((v.u >> 16) & 1)) >> 16);
}
__device__ inline float bf2f(unsigned u16) {
    union { unsigned u; float f; } v; v.u = u16 << 16;
    return v.f;
}

// ---------------- W transpose: W[256][128] f32 -> Wt[128][256] bf16 ----------
__global__ __launch_bounds__(256)
void wt_kernel(const float* __restrict__ W, unsigned short* __restrict__ Wt) {
    __shared__ float t[32][33];
    const int tx = threadIdx.x & 31, ty = threadIdx.x >> 5;
    const int k0 = (blockIdx.x >> 2) * 32, n0 = (blockIdx.x & 3) * 32;
#pragma unroll
    for (int i = 0; i < 32; i += 8)
        t[ty + i][tx] = W[(size_t)(k0 + ty + i) * DO + n0 + tx];
    __syncthreads();
#pragma unroll
    for (int i = 0; i < 32; i += 8)
        Wt[(size_t)(n0 + ty + i) * DI + k0 + tx] = f2bf(t[tx][ty + i]);
}

// ---------------- pack: xb = bf16(x * mask), pure streaming ------------------
// R6 control experiment + traffic cut. The m13 copy pattern (contiguous
// float4 reads, 2KB/wave; uint4 stores, 1KB/wave) is known-good for
// ~6.3 TB/s on MI355X. Reads 204.8 MB, writes 51.2 MB. Quantization point
// identical to the old in-gemm f2bf(x*m) -> bit-identical results.
// If THIS kernel also crawls at ~1.3 TB/s, the memory path / input
// placement is the bottleneck, not gemm structure.
__global__ __launch_bounds__(256)
void pack_kernel(const float* __restrict__ x, const float* __restrict__ mask,
                 unsigned short* __restrict__ xb) {
    const size_t n8 = (size_t)NN * DI / 8;   // 3.2e6 groups of 8 floats
    for (size_t i = (size_t)blockIdx.x * 256 + threadIdx.x; i < n8;
         i += (size_t)gridDim.x * 256) {
        const float4 a0 = ((const float4*)x)[2 * i];
        const float4 a1 = ((const float4*)x)[2 * i + 1];
        const float4 b0 = ((const float4*)mask)[2 * i];
        const float4 b1 = ((const float4*)mask)[2 * i + 1];
        union { unsigned short u[8]; uint4 q; } r;
        r.u[0] = f2bf(a0.x * b0.x); r.u[1] = f2bf(a0.y * b0.y);
        r.u[2] = f2bf(a0.z * b0.z); r.u[3] = f2bf(a0.w * b0.w);
        r.u[4] = f2bf(a1.x * b1.x); r.u[5] = f2bf(a1.y * b1.y);
        r.u[6] = f2bf(a1.z * b1.z); r.u[7] = f2bf(a1.w * b1.w);
        ((uint4*)xb)[i] = r.q;
    }
}

// ---------------- GEMM: h = bf16( xb @ W ), lean bf16 A ---------------------
// Post-mortem R5: four schedules (barrier-LDS / barrier-free / deep-burst /
// DMA-dbuf) all land 92-113 us at ~2 B/cyc/CU with every pipe idle -- the
// limiter is not intra-kernel scheduling. R6: A-stream pre-packed to bf16
// (51 MB, freshly L3-resident), 8 up-front 16B fragment loads per lane,
// L1-hot flat B, 64 MFMAs, no LDS, no barriers.
__global__ __launch_bounds__(256)
void gemm_kernel(const unsigned short* __restrict__ xb,
                 const unsigned short* __restrict__ Wt,
                 unsigned short* __restrict__ h) {
    const int tid  = threadIdx.x;
    const int lane = tid & 63;
    const int w    = tid >> 6;          // wave 0..3
    const int m0   = blockIdx.x * 64;
    const int mw   = w * 16;            // wave's 16-row slice
    const int l15  = lane & 15;
    const int l4   = lane >> 4;

    const int arow = m0 + mw + l15;     // clamped loads; guarded stores
    const unsigned short* ap =
        xb + (size_t)(arow < NN ? arow : 0) * DI + l4 * 8;

    // all 8 A fragments up front (independent 16B loads, L3-hot)
    bf16x8 af[8];
#pragma unroll
    for (int s = 0; s < 4; ++s) {
        af[2 * s]     = *(const bf16x8*)(ap + s * 64);
        af[2 * s + 1] = *(const bf16x8*)(ap + s * 64 + 32);
    }

    f32x4 acc[8];
#pragma unroll
    for (int ct = 0; ct < 8; ++ct) acc[ct] = (f32x4){0.f, 0.f, 0.f, 0.f};

#pragma unroll
    for (int s = 0; s < 4; ++s)
#pragma unroll
        for (int ks = 0; ks < 2; ++ks)
#pragma unroll
            for (int ct = 0; ct < 8; ++ct) {
                const bf16x8 b = *(const bf16x8*)(Wt +
                    (size_t)(ct * 16 + l15) * DI + s * 64 + ks * 32 + l4 * 8);
                acc[ct] = __builtin_amdgcn_mfma_f32_16x16x32_bf16(
                    af[2 * s + ks], b, acc[ct], 0, 0, 0);
            }

    // epilogue: D[row = l4*4+reg][col = l15]
#pragma unroll
    for (int ct = 0; ct < 8; ++ct)
#pragma unroll
        for (int reg = 0; reg < 4; ++reg) {
            const int row = m0 + mw + l4 * 4 + reg;
            if (row < NN)
                h[(size_t)row * DO + ct * 16 + l15] = f2bf(acc[ct][reg]);
        }
}

// ---------------- partition: edges -> fixed-slot bucket lists ---------------
// csr[b*CAP + i]; global bcnt is both cursor and final per-bucket count.
// R6: TILE 2048 -> 782 blocks (~3/CU) instead of 196 (0.76/CU).
__global__ __launch_bounds__(256)
void part_kernel(const int* __restrict__ erow, const int* __restrict__ ecol,
                 const float* __restrict__ ew, int* __restrict__ bcnt,
                 int2* __restrict__ csr) {
    __shared__ int cnt[NBK];
    __shared__ int base[NBK];
    const int t  = threadIdx.x;
    const int e0 = blockIdx.x * TILE;
    for (int k = t; k < NBK; k += 256) cnt[k] = 0;
    __syncthreads();
    for (int k = 0; k < TILE; k += 256) {
        const int e = e0 + k + t;
        if (e < NE) atomicAdd(&cnt[erow[e] >> 7], 1);
    }
    __syncthreads();
    for (int k = t; k < NBK; k += 256) {
        const int c = cnt[k];
        base[k] = c ? atomicAdd(&bcnt[k], c) : 0;
        cnt[k] = 0;
    }
    __syncthreads();
    for (int k = 0; k < TILE; k += 256) {
        const int e = e0 + k + t;
        if (e < NE) {
            const int row = erow[e];
            const int bk  = row >> 7;
            const int pos = atomicAdd(&cnt[bk], 1);
            int2 v;
            v.x = ((row & 127) << 17) | ecol[e];   // col < 2^17
            v.y = __float_as_int(ew[e]);
            csr[(size_t)bk * CAP + base[bk] + pos] = v;
        }
    }
}

// ---------------- bucket gather: LDS counting sort + register gather --------
// 512 threads/block (grid fixed at 782 -> 3 blocks/CU; wider block = more
// resident waves for latency hiding on random h reads).
__global__ __launch_bounds__(512)
void bgather_kernel(const unsigned short* __restrict__ h,
                    const int* __restrict__ bcnt,
                    const int2* __restrict__ csr, float* __restrict__ out) {
    __shared__ int2 se[CAP];            // sorted edges
    __shared__ int  s_cnt[BROWS];       // histogram -> cursor
    __shared__ int  s_start[BROWS + 1];
    __shared__ int  wtot;
    const int b = blockIdx.x, t = threadIdx.x;
    const int n = bcnt[b];
    const int2* ebase = csr + (size_t)b * CAP;

    if (t < BROWS) s_cnt[t] = 0;
    __syncthreads();
    // pass 1: histogram by row-offset
    for (int j = t; j < n; j += 512)
        atomicAdd(&s_cnt[((unsigned)ebase[j].x) >> 17], 1);
    __syncthreads();
    // scan 128 bins
    const int lane = t & 63;
    int c = 0;
    if (t < BROWS) c = s_cnt[t];
    int v = c;
#pragma unroll
    for (int off = 1; off < 64; off <<= 1) {
        const int nn = __shfl_up(v, off, 64);
        if (lane >= off) v += nn;
    }
    if (t == 63) wtot = v;
    __syncthreads();
    if (t < BROWS) {
        const int excl = v - c + (t >= 64 ? wtot : 0);
        s_start[t] = excl;
        s_cnt[t]   = excl;   // reuse as scatter cursor
    }
    if (t == 0) s_start[BROWS] = n;
    __syncthreads();
    // pass 2: scatter into row-sorted order
    for (int j = t; j < n; j += 512) {
        const int2 cw  = ebase[j];
        const int  pos = atomicAdd(&s_cnt[((unsigned)cw.x) >> 17], 1);
        se[pos] = cw;
    }
    __syncthreads();

    // gather: 32 groups of 16 lanes; group g handles rows g, g+32, g+64, g+96
    const int l16 = t & 15, g = t >> 4;
    const int row0 = b * BROWS;
#pragma unroll
    for (int rp = 0; rp < 4; ++rp) {
        const int r  = rp * 32 + g;
        const int gr = row0 + r;
        const int rs = s_start[r], re = s_start[r + 1];
        float acc[8];
#pragma unroll
        for (int i = 0; i < 8; ++i) acc[i] = 0.f;
        int j = rs;
        for (; j + 2 <= re; j += 2) {
            const int2 cw0 = se[j], cw1 = se[j + 1];
            const float w0 = __int_as_float(cw0.y);
            const float w1 = __int_as_float(cw1.y);
            const uint4 q0 = *(const uint4*)(h + (size_t)(cw0.x & 0x1FFFF) * DO + l16 * 8);
            const uint4 q1 = *(const uint4*)(h + (size_t)(cw1.x & 0x1FFFF) * DO + l16 * 8);
            const unsigned* u0 = (const unsigned*)&q0;
            const unsigned* u1 = (const unsigned*)&q1;
#pragma unroll
            for (int i = 0; i < 4; ++i) {
                acc[2 * i + 0] += w0 * bf2f(u0[i] & 0xFFFF) + w1 * bf2f(u1[i] & 0xFFFF);
                acc[2 * i + 1] += w0 * bf2f(u0[i] >> 16)    + w1 * bf2f(u1[i] >> 16);
            }
        }
        if (j < re) {
            const int2 cw = se[j];
            const float w = __int_as_float(cw.y);
            const uint4 q = *(const uint4*)(h + (size_t)(cw.x & 0x1FFFF) * DO + l16 * 8);
            const unsigned* u = (const unsigned*)&q;
#pragma unroll
            for (int i = 0; i < 4; ++i) {
                acc[2 * i + 0] += w * bf2f(u[i] & 0xFFFF);
                acc[2 * i + 1] += w * bf2f(u[i] >> 16);
            }
        }
        if (gr < NN) {
            float* op = out + (size_t)gr * DO + l16 * 8;
            *(float4*)(op + 0) = make_float4(fmaxf(acc[0], 0.f), fmaxf(acc[1], 0.f),
                                             fmaxf(acc[2], 0.f), fmaxf(acc[3], 0.f));
            *(float4*)(op + 4) = make_float4(fmaxf(acc[4], 0.f), fmaxf(acc[5], 0.f),
                                             fmaxf(acc[6], 0.f), fmaxf(acc[7], 0.f));
        }
    }
}

extern "C" void kernel_launch(void* const* d_in, const int* in_sizes, int n_in,
                              void* d_out, int out_size, void* d_ws, size_t ws_size,
                              hipStream_t stream) {
    const float* x    = (const float*)d_in[0];
    const float* mask = (const float*)d_in[1];
    const float* W    = (const float*)d_in[2];
    const int*   erow = (const int*)d_in[3];
    const int*   ecol = (const int*)d_in[4];
    const float* ew   = (const float*)d_in[5];
    float* out = (float*)d_out;

    char* p = (char*)d_ws;
    unsigned short* h  = (unsigned short*)p;  p += (size_t)NN * DO * 2;   // 25.6 MB
    unsigned short* Wt = (unsigned short*)p;  p += (size_t)DO * DI * 2;   // 64 KB
    int* bcnt = (int*)p;                      p += 3200;
    int2* csr = (int2*)p;                     p += (size_t)NBK * CAP * 8; // 16.8 MB
    unsigned short* xb = (unsigned short*)p;  // NN*DI*2 = 51.2 MB

    hipMemsetAsync(bcnt, 0, NBK * sizeof(int), stream);

    wt_kernel<<<32, 256, 0, stream>>>(W, Wt);
    pack_kernel<<<2048, 256, 0, stream>>>(x, mask, xb);
    gemm_kernel<<<(NN + 63) / 64, 256, 0, stream>>>(xb, Wt, h);
    part_kernel<<<(NE + TILE - 1) / TILE, 256, 0, stream>>>(erow, ecol, ew,
                                                            bcnt, csr);
    bgather_kernel<<<NBK, 512, 0, stream>>>(h, bcnt, csr, out);
}

// Round 7
// 358.711 us; speedup vs baseline: 1.2096x; 1.2096x over previous
//
#include <hip/hip_runtime.h>

constexpr int NN = 100000;   // nodes
constexpr int DI = 256;      // in features
constexpr int DO = 128;      // out features
constexpr int NE = 1600000;  // edges

constexpr int BROWS = 128;                        // rows per bucket
constexpr int NBK   = (NN + BROWS - 1) / BROWS;   // 782 buckets
constexpr int TILE  = 2048;                       // edges per partition block
constexpr int CAP   = 2688;                       // slots per bucket (mean 2046, sd ~45)

constexpr int NGB = (NN + 63) / 64;               // 1563 gemm blocks
constexpr int NPB = (NE + TILE - 1) / TILE;       // 782 part blocks

typedef __bf16 bf16x8 __attribute__((ext_vector_type(8)));
typedef float  f32x4  __attribute__((ext_vector_type(4)));

__device__ inline unsigned short f2bf(float f) {
    union { float f; unsigned u; } v; v.f = f;
    return (unsigned short)((v.u + 0x7FFF + ((v.u >> 16) & 1)) >> 16);
}
__device__ inline float bf2f(unsigned u16) {
    union { unsigned u; float f; } v; v.u = u16 << 16;
    return v.f;
}

// ---------------- W transpose: W[256][128] f32 -> Wt[128][256] bf16 ----------
__global__ __launch_bounds__(256)
void wt_kernel(const float* __restrict__ W, unsigned short* __restrict__ Wt) {
    __shared__ float t[32][33];
    const int tx = threadIdx.x & 31, ty = threadIdx.x >> 5;
    const int k0 = (blockIdx.x >> 2) * 32, n0 = (blockIdx.x & 3) * 32;
#pragma unroll
    for (int i = 0; i < 32; i += 8)
        t[ty + i][tx] = W[(size_t)(k0 + ty + i) * DO + n0 + tx];
    __syncthreads();
#pragma unroll
    for (int i = 0; i < 32; i += 8)
        Wt[(size_t)(n0 + ty + i) * DI + k0 + tx] = f2bf(t[tx][ty + i]);
}

// ---------------- fused GEMM + partition (block-range fusion) ---------------
// Post-mortem R6: the pure-streaming control (pack) hit only 1.75 TB/s HBM
// (~3 TB/s effective with L3) -> this box's streaming ceiling is ~2.5-3 TB/s
// effective. The baseline LDS gemm (92 us, 230 MB effective = 2.5 TB/s) was
// ALREADY at that ceiling; R3-R6 scheduling variants were chasing a
// non-problem. Revert to the proven gemm body verbatim.
// New lever: part_kernel is independent of gemm (only bgather consumes
// both), but the stream serializes kernels and events/multi-stream are
// forbidden under graph capture. Block-range fusion gives legal overlap:
// blocks [0,NGB) = gemm, [NGB,NGB+NPB) = part; LDS overlaid via union;
// block-uniform branch. Two latency-bound phases co-resident -> max not sum.
__global__ __launch_bounds__(256)
void gemm_part_kernel(const float* __restrict__ x, const float* __restrict__ mask,
                      const unsigned short* __restrict__ Wt,
                      unsigned short* __restrict__ h,
                      const int* __restrict__ erow, const int* __restrict__ ecol,
                      const float* __restrict__ ew, int* __restrict__ bcnt,
                      int2* __restrict__ csr) {
    __shared__ union {
        struct { unsigned short As[64][72]; unsigned short Bs[128][72]; } g; // 27648 B
        struct { int cnt[NBK]; int base[NBK]; } p;                           //  6256 B
    } sm;

    if (blockIdx.x < NGB) {
        // ---------------- gemm body (proven 92 us baseline, verbatim) ------
        const int tid  = threadIdx.x;
        const int lane = tid & 63;
        const int w    = tid >> 6;          // wave 0..3
        const int m0   = blockIdx.x * 64;
        const int mw   = w * 16;            // wave's 16-row slice
        const int l15  = lane & 15;
        const int l4   = lane >> 4;

        f32x4 acc[8];
#pragma unroll
        for (int ct = 0; ct < 8; ++ct) acc[ct] = (f32x4){0.f, 0.f, 0.f, 0.f};

        const int lr = tid >> 4;         // 0..15: row within 16-row group
        const int lk = (tid & 15) * 4;   // 0..60: k offset (float4)

        float4 xv[4], mv[4];
        const float4 z4 = make_float4(0.f, 0.f, 0.f, 0.f);

        // prefetch kc = 0
#pragma unroll
        for (int p = 0; p < 4; ++p) {
            const int r = m0 + p * 16 + lr;
            if (r < NN) {
                xv[p] = *(const float4*)(x    + (size_t)r * DI + lk);
                mv[p] = *(const float4*)(mask + (size_t)r * DI + lk);
            } else { xv[p] = z4; mv[p] = z4; }
        }

        for (int kc = 0; kc < DI; kc += 64) {
            __syncthreads();   // prev MFMA done reading LDS
            // store prefetched A (convert to bf16)
#pragma unroll
            for (int p = 0; p < 4; ++p) {
                ushort4 pk;
                pk.x = f2bf(xv[p].x * mv[p].x); pk.y = f2bf(xv[p].y * mv[p].y);
                pk.z = f2bf(xv[p].z * mv[p].z); pk.w = f2bf(xv[p].w * mv[p].w);
                *(ushort4*)&sm.g.As[p * 16 + lr][lk] = pk;
            }
            // stage B (L2-hot, 16 KB)
            {
                const int kl = (tid & 7) * 8;
#pragma unroll
                for (int p = 0; p < 4; ++p) {
                    const int n = p * 32 + (tid >> 3);
                    *(uint4*)&sm.g.Bs[n][kl] =
                        *(const uint4*)(Wt + (size_t)n * DI + kc + kl);
                }
            }
            // prefetch next K-tile (overlaps with MFMA below)
            if (kc + 64 < DI) {
#pragma unroll
                for (int p = 0; p < 4; ++p) {
                    const int r = m0 + p * 16 + lr;
                    if (r < NN) {
                        xv[p] = *(const float4*)(x    + (size_t)r * DI + kc + 64 + lk);
                        mv[p] = *(const float4*)(mask + (size_t)r * DI + kc + 64 + lk);
                    } else { xv[p] = z4; mv[p] = z4; }
                }
            }
            __syncthreads();
#pragma unroll
            for (int ks = 0; ks < 2; ++ks) {
                const int ko = ks * 32 + l4 * 8;
                const bf16x8 a0 = *(const bf16x8*)&sm.g.As[mw + l15][ko];
#pragma unroll
                for (int ct = 0; ct < 8; ++ct) {
                    const bf16x8 b = *(const bf16x8*)&sm.g.Bs[ct * 16 + l15][ko];
                    acc[ct] = __builtin_amdgcn_mfma_f32_16x16x32_bf16(a0, b, acc[ct], 0, 0, 0);
                }
            }
        }
        // epilogue: D[row = l4*4+reg][col = l15]
#pragma unroll
        for (int ct = 0; ct < 8; ++ct)
#pragma unroll
            for (int reg = 0; reg < 4; ++reg) {
                const int row = m0 + mw + l4 * 4 + reg;
                if (row < NN)
                    h[(size_t)row * DO + ct * 16 + l15] = f2bf(acc[ct][reg]);
            }
    } else {
        // ---------------- partition body -----------------------------------
        const int t  = threadIdx.x;
        const int e0 = (blockIdx.x - NGB) * TILE;
        for (int k = t; k < NBK; k += 256) sm.p.cnt[k] = 0;
        __syncthreads();
        for (int k = 0; k < TILE; k += 256) {
            const int e = e0 + k + t;
            if (e < NE) atomicAdd(&sm.p.cnt[erow[e] >> 7], 1);
        }
        __syncthreads();
        for (int k = t; k < NBK; k += 256) {
            const int c = sm.p.cnt[k];
            sm.p.base[k] = c ? atomicAdd(&bcnt[k], c) : 0;
            sm.p.cnt[k] = 0;
        }
        __syncthreads();
        for (int k = 0; k < TILE; k += 256) {
            const int e = e0 + k + t;
            if (e < NE) {
                const int row = erow[e];
                const int bk  = row >> 7;
                const int pos = atomicAdd(&sm.p.cnt[bk], 1);
                int2 v;
                v.x = ((row & 127) << 17) | ecol[e];   // col < 2^17
                v.y = __float_as_int(ew[e]);
                csr[(size_t)bk * CAP + sm.p.base[bk] + pos] = v;
            }
        }
    }
}

// ---------------- bucket gather: LDS counting sort + register gather --------
// 512 threads/block (grid fixed at 782 -> 3 blocks/CU; wider block = more
// resident waves for latency hiding on random h reads).
__global__ __launch_bounds__(512)
void bgather_kernel(const unsigned short* __restrict__ h,
                    const int* __restrict__ bcnt,
                    const int2* __restrict__ csr, float* __restrict__ out) {
    __shared__ int2 se[CAP];            // sorted edges
    __shared__ int  s_cnt[BROWS];       // histogram -> cursor
    __shared__ int  s_start[BROWS + 1];
    __shared__ int  wtot;
    const int b = blockIdx.x, t = threadIdx.x;
    const int n = bcnt[b];
    const int2* ebase = csr + (size_t)b * CAP;

    if (t < BROWS) s_cnt[t] = 0;
    __syncthreads();
    // pass 1: histogram by row-offset
    for (int j = t; j < n; j += 512)
        atomicAdd(&s_cnt[((unsigned)ebase[j].x) >> 17], 1);
    __syncthreads();
    // scan 128 bins
    const int lane = t & 63;
    int c = 0;
    if (t < BROWS) c = s_cnt[t];
    int v = c;
#pragma unroll
    for (int off = 1; off < 64; off <<= 1) {
        const int nn = __shfl_up(v, off, 64);
        if (lane >= off) v += nn;
    }
    if (t == 63) wtot = v;
    __syncthreads();
    if (t < BROWS) {
        const int excl = v - c + (t >= 64 ? wtot : 0);
        s_start[t] = excl;
        s_cnt[t]   = excl;   // reuse as scatter cursor
    }
    if (t == 0) s_start[BROWS] = n;
    __syncthreads();
    // pass 2: scatter into row-sorted order
    for (int j = t; j < n; j += 512) {
        const int2 cw  = ebase[j];
        const int  pos = atomicAdd(&s_cnt[((unsigned)cw.x) >> 17], 1);
        se[pos] = cw;
    }
    __syncthreads();

    // gather: 32 groups of 16 lanes; group g handles rows g, g+32, g+64, g+96
    const int l16 = t & 15, g = t >> 4;
    const int row0 = b * BROWS;
#pragma unroll
    for (int rp = 0; rp < 4; ++rp) {
        const int r  = rp * 32 + g;
        const int gr = row0 + r;
        const int rs = s_start[r], re = s_start[r + 1];
        float acc[8];
#pragma unroll
        for (int i = 0; i < 8; ++i) acc[i] = 0.f;
        int j = rs;
        for (; j + 2 <= re; j += 2) {
            const int2 cw0 = se[j], cw1 = se[j + 1];
            const float w0 = __int_as_float(cw0.y);
            const float w1 = __int_as_float(cw1.y);
            const uint4 q0 = *(const uint4*)(h + (size_t)(cw0.x & 0x1FFFF) * DO + l16 * 8);
            const uint4 q1 = *(const uint4*)(h + (size_t)(cw1.x & 0x1FFFF) * DO + l16 * 8);
            const unsigned* u0 = (const unsigned*)&q0;
            const unsigned* u1 = (const unsigned*)&q1;
#pragma unroll
            for (int i = 0; i < 4; ++i) {
                acc[2 * i + 0] += w0 * bf2f(u0[i] & 0xFFFF) + w1 * bf2f(u1[i] & 0xFFFF);
                acc[2 * i + 1] += w0 * bf2f(u0[i] >> 16)    + w1 * bf2f(u1[i] >> 16);
            }
        }
        if (j < re) {
            const int2 cw = se[j];
            const float w = __int_as_float(cw.y);
            const uint4 q = *(const uint4*)(h + (size_t)(cw.x & 0x1FFFF) * DO + l16 * 8);
            const unsigned* u = (const unsigned*)&q;
#pragma unroll
            for (int i = 0; i < 4; ++i) {
                acc[2 * i + 0] += w * bf2f(u[i] & 0xFFFF);
                acc[2 * i + 1] += w * bf2f(u[i] >> 16);
            }
        }
        if (gr < NN) {
            float* op = out + (size_t)gr * DO + l16 * 8;
            *(float4*)(op + 0) = make_float4(fmaxf(acc[0], 0.f), fmaxf(acc[1], 0.f),
                                             fmaxf(acc[2], 0.f), fmaxf(acc[3], 0.f));
            *(float4*)(op + 4) = make_float4(fmaxf(acc[4], 0.f), fmaxf(acc[5], 0.f),
                                             fmaxf(acc[6], 0.f), fmaxf(acc[7], 0.f));
        }
    }
}

extern "C" void kernel_launch(void* const* d_in, const int* in_sizes, int n_in,
                              void* d_out, int out_size, void* d_ws, size_t ws_size,
                              hipStream_t stream) {
    const float* x    = (const float*)d_in[0];
    const float* mask = (const float*)d_in[1];
    const float* W    = (const float*)d_in[2];
    const int*   erow = (const int*)d_in[3];
    const int*   ecol = (const int*)d_in[4];
    const float* ew   = (const float*)d_in[5];
    float* out = (float*)d_out;

    char* p = (char*)d_ws;
    unsigned short* h  = (unsigned short*)p;  p += (size_t)NN * DO * 2;   // 25.6 MB
    unsigned short* Wt = (unsigned short*)p;  p += (size_t)DO * DI * 2;   // 64 KB
    int* bcnt = (int*)p;                      p += 3200;
    int2* csr = (int2*)p;                     // NBK*CAP*8 = 16.8 MB

    hipMemsetAsync(bcnt, 0, NBK * sizeof(int), stream);

    wt_kernel<<<32, 256, 0, stream>>>(W, Wt);
    gemm_part_kernel<<<NGB + NPB, 256, 0, stream>>>(x, mask, Wt, h,
                                                    erow, ecol, ew, bcnt, csr);
    bgather_kernel<<<NBK, 512, 0, stream>>>(h, bcnt, csr, out);
}